// Round 17
// baseline (254.334 us; speedup 1.0000x reference)
//
#include <hip/hip_runtime.h>
#include <hip/hip_bf16.h>

#define N_NODES 100000
#define N_EDGES 1600000
#define NBUCK 196                 // ceil(100000/512) node buckets (512 nodes each)
#define BCAP 12288                // per-bucket pk capacity (avg 8192, +45 sigma)
#define CHUNK 4096                // edges per partition block
#define PART_BLOCKS 391           // ceil(1600000/4096)
#define CONV_BLOCKS 6250          // x float4 groups / 256
#define CAP32 32                  // per-bucket LDS list slots in partition
#define LCAP 96                   // per-node LDS list capacity (P(deg>96)~1e-40)
#define MSTRIDE 36                // LDS mean row stride (words): 2-way alias (free)

// fp32 inputs (confirmed R3-vs-R5); bf16 MFMA internals; fp32 out.
// R14: identity node->slot mapping. R15/R16: CSR chain was the hidden half of
// the budget -> R17 removes csr_build: layer blocks build per-node neighbor
// lists in LDS straight from pk (each block = 1/8 bucket).

typedef __hip_bfloat16 bf16;
typedef short short8 __attribute__((ext_vector_type(8)));
typedef float f32x4 __attribute__((ext_vector_type(4)));
typedef unsigned int uint;

__device__ __forceinline__ short f2bs(float f) {
    bf16 h = __float2bfloat16(f);
    short s; __builtin_memcpy(&s, &h, 2); return s;
}
__device__ __forceinline__ float lo_bf(uint w) {
    uint v = w << 16; float f; __builtin_memcpy(&f, &v, 4); return f;
}
__device__ __forceinline__ float hi_bf(uint w) {
    uint v = w & 0xFFFF0000u; float f; __builtin_memcpy(&f, &v, 4); return f;
}
__device__ __forceinline__ uint pack2(float a, float b) {
    return (uint)(unsigned short)f2bs(a) | ((uint)(unsigned short)f2bs(b) << 16);
}
__device__ __forceinline__ short8 load8bf(const bf16* __restrict__ p, long idx) {
    return *(const short8*)((const short*)p + idx);
}

// ---- prep: partition (blocks 0..390) + x/weight convert (rest) ---------
// Single-pass LDS bucket lists (32 slots) + global overflow via gcur
// (disjoint atomic reservation). gcur[b] ends as the exact bucket count.
// Payload: src (17b) | local dst (9b) << 17.
__global__ __launch_bounds__(256) void prep_kernel(
    const float* __restrict__ x, bf16* __restrict__ xb,
    const float* __restrict__ W1l, const float* __restrict__ W1r,
    const float* __restrict__ W2l, const float* __restrict__ W2r,
    bf16* __restrict__ wb,
    const int* __restrict__ src, const int* __restrict__ dst,
    int* __restrict__ gcur, int* __restrict__ pk)
{
    __shared__ int pl[256 * CAP32];          // 32 KB
    __shared__ int cnt[256], gb[256];
    int t = threadIdx.x;

    if (blockIdx.x >= PART_BLOCKS) {         // conversion block
        int cb = blockIdx.x - PART_BLOCKS;   // 0..6249
        int i = cb * 256 + t;                // float4 group (1.6M exact)
        float4 v = ((const float4*)x)[i];
        uint2 o;
        o.x = pack2(v.x, v.y);
        o.y = pack2(v.z, v.w);
        ((uint2*)xb)[i] = o;
        if (cb == 0) {
            for (int k = t; k < 16384; k += 256) {
                float vv;
                if (k < 4096)       vv = W1l[k];
                else if (k < 8192)  vv = W1r[k - 4096];
                else if (k < 12288) vv = W2l[k - 8192];
                else                vv = W2r[k - 12288];
                wb[k] = __float2bfloat16(vv);
            }
        }
        return;
    }

    cnt[t] = 0;
    __syncthreads();
    int e0 = blockIdx.x * CHUNK;
    for (int i = t; i < CHUNK; i += 256) {
        int e = e0 + i;
        if (e < N_EDGES) {
            int d = dst[e];
            int b = d >> 9;
            int payload = src[e] | ((d & 511) << 17);
            int p = atomicAdd(&cnt[b], 1);
            if (p < CAP32) {
                pl[b * CAP32 + p] = payload;
            } else {                          // rare overflow (~0.3% of edges)
                int g = atomicAdd(&gcur[b], 1);
                if (g < BCAP) pk[b * BCAP + g] = payload;
            }
        }
    }
    __syncthreads();
    {
        int c = cnt[t] < CAP32 ? cnt[t] : CAP32;
        gb[t] = c > 0 ? atomicAdd(&gcur[t], c) : 0;
        cnt[t] = c;
    }
    __syncthreads();
    for (int i = t; i < 256 * CAP32; i += 256) {
        int b = i >> 5;
        int pos = i & (CAP32 - 1);
        if (pos < cnt[b]) {
            int g = gb[b] + pos;
            if (g < BCAP) pk[b * BCAP + g] = pl[i];
        }
    }
}

// ---- Fused layers ------------------------------------------------------
// Phase 0: build per-node neighbor lists in LDS from this block's 1/8-bucket
//          window of pk (coalesced scan + filter).
// Phase 1: gather-mean (8 lanes/node, lane=16B chunk, unroll-8, indices from
//          LDS broadcast reads) -> mean_l.
// Phase 2: waves 0-3 run the verified MFMA body.

__device__ __forceinline__ void build_and_gather(
    const bf16* __restrict__ feat, const int* __restrict__ gcur,
    const int* __restrict__ pk, int b, int hs,
    int* __restrict__ lists_l, int* __restrict__ cnt_l, uint* __restrict__ mean_l)
{
    int t = threadIdx.x;
    if (t < 64) cnt_l[t] = 0;
    __syncthreads();
    int base = b * BCAP;
    int cnt = gcur[b];
    if (cnt > BCAP) cnt = BCAP;
    for (int i = t; i < cnt; i += 512) {
        int v = pk[base + i];
        int ld = (v >> 17) - hs;
        if ((unsigned)ld < 64u) {
            int p = atomicAdd(&cnt_l[ld], 1);
            if (p < LCAP) lists_l[ld * LCAP + p] = v & 0x1FFFF;
        }
    }
    __syncthreads();

    int wave = t >> 6, lane = t & 63;
    int g = lane >> 3, ci = lane & 7;
    int nl = wave * 8 + g;
    int deg = cnt_l[nl];
    if (deg > LCAP) deg = LCAP;
    const int* lst = lists_l + nl * LCAP;
    const uint* fw = (const uint*)feat;
    float a0 = 0.f, a1 = 0.f, a2 = 0.f, a3 = 0.f;
    float a4 = 0.f, a5 = 0.f, a6 = 0.f, a7 = 0.f;
    int i = 0;
    for (; i + 7 < deg; i += 8) {                  // 8 rows in flight per lane
        int s0 = lst[i],     s1 = lst[i + 1], s2 = lst[i + 2], s3 = lst[i + 3];
        int s4 = lst[i + 4], s5 = lst[i + 5], s6 = lst[i + 6], s7 = lst[i + 7];
        uint4 w0 = *(const uint4*)(fw + (long)s0 * 32 + ci * 4);
        uint4 w1 = *(const uint4*)(fw + (long)s1 * 32 + ci * 4);
        uint4 w2 = *(const uint4*)(fw + (long)s2 * 32 + ci * 4);
        uint4 w3 = *(const uint4*)(fw + (long)s3 * 32 + ci * 4);
        uint4 w4 = *(const uint4*)(fw + (long)s4 * 32 + ci * 4);
        uint4 w5 = *(const uint4*)(fw + (long)s5 * 32 + ci * 4);
        uint4 w6 = *(const uint4*)(fw + (long)s6 * 32 + ci * 4);
        uint4 w7 = *(const uint4*)(fw + (long)s7 * 32 + ci * 4);
        a0 += lo_bf(w0.x) + lo_bf(w1.x) + lo_bf(w2.x) + lo_bf(w3.x)
            + lo_bf(w4.x) + lo_bf(w5.x) + lo_bf(w6.x) + lo_bf(w7.x);
        a1 += hi_bf(w0.x) + hi_bf(w1.x) + hi_bf(w2.x) + hi_bf(w3.x)
            + hi_bf(w4.x) + hi_bf(w5.x) + hi_bf(w6.x) + hi_bf(w7.x);
        a2 += lo_bf(w0.y) + lo_bf(w1.y) + lo_bf(w2.y) + lo_bf(w3.y)
            + lo_bf(w4.y) + lo_bf(w5.y) + lo_bf(w6.y) + lo_bf(w7.y);
        a3 += hi_bf(w0.y) + hi_bf(w1.y) + hi_bf(w2.y) + hi_bf(w3.y)
            + hi_bf(w4.y) + hi_bf(w5.y) + hi_bf(w6.y) + hi_bf(w7.y);
        a4 += lo_bf(w0.z) + lo_bf(w1.z) + lo_bf(w2.z) + lo_bf(w3.z)
            + lo_bf(w4.z) + lo_bf(w5.z) + lo_bf(w6.z) + lo_bf(w7.z);
        a5 += hi_bf(w0.z) + hi_bf(w1.z) + hi_bf(w2.z) + hi_bf(w3.z)
            + hi_bf(w4.z) + hi_bf(w5.z) + hi_bf(w6.z) + hi_bf(w7.z);
        a6 += lo_bf(w0.w) + lo_bf(w1.w) + lo_bf(w2.w) + lo_bf(w3.w)
            + lo_bf(w4.w) + lo_bf(w5.w) + lo_bf(w6.w) + lo_bf(w7.w);
        a7 += hi_bf(w0.w) + hi_bf(w1.w) + hi_bf(w2.w) + hi_bf(w3.w)
            + hi_bf(w4.w) + hi_bf(w5.w) + hi_bf(w6.w) + hi_bf(w7.w);
    }
    for (; i + 1 < deg; i += 2) {
        int s0 = lst[i], s1 = lst[i + 1];
        uint4 w0 = *(const uint4*)(fw + (long)s0 * 32 + ci * 4);
        uint4 w1 = *(const uint4*)(fw + (long)s1 * 32 + ci * 4);
        a0 += lo_bf(w0.x) + lo_bf(w1.x); a1 += hi_bf(w0.x) + hi_bf(w1.x);
        a2 += lo_bf(w0.y) + lo_bf(w1.y); a3 += hi_bf(w0.y) + hi_bf(w1.y);
        a4 += lo_bf(w0.z) + lo_bf(w1.z); a5 += hi_bf(w0.z) + hi_bf(w1.z);
        a6 += lo_bf(w0.w) + lo_bf(w1.w); a7 += hi_bf(w0.w) + hi_bf(w1.w);
    }
    if (i < deg) {
        int s = lst[i];
        uint4 w = *(const uint4*)(fw + (long)s * 32 + ci * 4);
        a0 += lo_bf(w.x); a1 += hi_bf(w.x);
        a2 += lo_bf(w.y); a3 += hi_bf(w.y);
        a4 += lo_bf(w.z); a5 += hi_bf(w.z);
        a6 += lo_bf(w.w); a7 += hi_bf(w.w);
    }
    float inv = deg > 0 ? 1.0f / (float)deg : 0.0f;
    uint4 qv;
    qv.x = pack2(a0 * inv, a1 * inv);
    qv.y = pack2(a2 * inv, a3 * inv);
    qv.z = pack2(a4 * inv, a5 * inv);
    qv.w = pack2(a6 * inv, a7 * inv);
    *(uint4*)(mean_l + nl * MSTRIDE + ci * 4) = qv;
}

// wlb = [Wl | Wr] bf16, each 4096
__device__ __forceinline__ short8 load_bfrag(
    const bf16* __restrict__ wlb, int f, int c, int quad)
{
    if (c < 2) return load8bf(wlb, (long)f * 64 + c * 32 + quad * 8);
    return load8bf(wlb, 4096 + (long)f * 64 + (c - 2) * 32 + quad * 8);
}

__global__ __launch_bounds__(512) void layer1_fused(
    const bf16* __restrict__ xb, const int* __restrict__ gcur,
    const int* __restrict__ pk, const bf16* __restrict__ wlb,
    const float* __restrict__ bl, bf16* __restrict__ h_out)
{
    __shared__ int lists_l[64 * LCAP];     // 24 KB
    __shared__ int cnt_l[64];
    __shared__ uint mean_l[64 * MSTRIDE];  // 9.2 KB
    int b = blockIdx.x >> 3;               // bucket
    int hs = (blockIdx.x & 7) * 64;        // local node window start
    int nb0 = (b << 9) + hs;
    build_and_gather(xb, gcur, pk, b, hs, lists_l, cnt_l, mean_l);
    __syncthreads();
    int tid = threadIdx.x;
    int wave = tid >> 6, lane = tid & 63;
    if (wave >= 4) return;
    int quad = lane >> 4, n16 = lane & 15;
    int nb = nb0 + wave * 16;
    int ln = wave * 16 + n16;

    int node_a = nb + n16;
    int na = node_a < N_NODES ? node_a : N_NODES - 1;
    short8 a[4];
#pragma unroll
    for (int c = 0; c < 2; c++)
        a[c] = *(const short8*)(mean_l + ln * MSTRIDE + c * 16 + quad * 4);
#pragma unroll
    for (int c = 0; c < 2; c++)
        a[2 + c] = load8bf(xb, (long)na * 64 + c * 32 + quad * 8);

#pragma unroll
    for (int t = 0; t < 4; t++) {
        int f = 16 * t + n16;
        f32x4 acc = {0.f, 0.f, 0.f, 0.f};
#pragma unroll
        for (int c = 0; c < 4; c++) {
            short8 bfr = load_bfrag(wlb, f, c, quad);
            acc = __builtin_amdgcn_mfma_f32_16x16x32_bf16(a[c], bfr, acc, 0, 0, 0);
        }
        float bias = bl[f];
#pragma unroll
        for (int r = 0; r < 4; r++) {
            int node = nb + quad * 4 + r;
            if (node < N_NODES)
                h_out[(long)node * 64 + f] = __float2bfloat16(fmaxf(acc[r] + bias, 0.0f));
        }
    }
}

__global__ __launch_bounds__(512) void layer2_fused(
    const bf16* __restrict__ h1, const int* __restrict__ gcur,
    const int* __restrict__ pk, const bf16* __restrict__ wlb,
    const float* __restrict__ bl, const float* __restrict__ Wlin,
    float* __restrict__ s_src, float* __restrict__ s_dst)
{
    __shared__ int lists_l[64 * LCAP];
    __shared__ int cnt_l[64];
    __shared__ uint mean_l[64 * MSTRIDE];
    int b = blockIdx.x >> 3;
    int hs = (blockIdx.x & 7) * 64;
    int nb0 = (b << 9) + hs;
    build_and_gather(h1, gcur, pk, b, hs, lists_l, cnt_l, mean_l);
    __syncthreads();
    int tid = threadIdx.x;
    int wave = tid >> 6, lane = tid & 63;
    if (wave >= 4) return;
    int quad = lane >> 4, n16 = lane & 15;
    int nb = nb0 + wave * 16;
    int ln = wave * 16 + n16;

    int node_a = nb + n16;
    int na = node_a < N_NODES ? node_a : N_NODES - 1;
    short8 a[4];
#pragma unroll
    for (int c = 0; c < 2; c++)
        a[c] = *(const short8*)(mean_l + ln * MSTRIDE + c * 16 + quad * 4);
#pragma unroll
    for (int c = 0; c < 2; c++)
        a[2 + c] = load8bf(h1, (long)na * 64 + c * 32 + quad * 8);

    float sa[4] = {0.f, 0.f, 0.f, 0.f};
    float sb[4] = {0.f, 0.f, 0.f, 0.f};
#pragma unroll
    for (int t = 0; t < 4; t++) {
        int f = 16 * t + n16;
        f32x4 acc = {0.f, 0.f, 0.f, 0.f};
#pragma unroll
        for (int c = 0; c < 4; c++) {
            short8 bfr = load_bfrag(wlb, f, c, quad);
            acc = __builtin_amdgcn_mfma_f32_16x16x32_bf16(a[c], bfr, acc, 0, 0, 0);
        }
        float bias = bl[f];
        float wa = Wlin[f];
        float wb = Wlin[64 + f];
#pragma unroll
        for (int r = 0; r < 4; r++) {
            float h = fmaxf(acc[r] + bias, 0.0f);
            sa[r] += h * wa;
            sb[r] += h * wb;
        }
    }
#pragma unroll
    for (int m = 1; m < 16; m <<= 1) {
#pragma unroll
        for (int r = 0; r < 4; r++) {
            sa[r] += __shfl_xor(sa[r], m);
            sb[r] += __shfl_xor(sb[r], m);
        }
    }
    if (n16 == 0) {
#pragma unroll
        for (int r = 0; r < 4; r++) {
            int node = nb + quad * 4 + r;
            if (node < N_NODES) { s_src[node] = sa[r]; s_dst[node] = sb[r]; }
        }
    }
}

__global__ __launch_bounds__(256) void edge_out_kernel(
    const int* __restrict__ src, const int* __restrict__ dst,
    const float* __restrict__ s_src, const float* __restrict__ s_dst,
    const float* __restrict__ blin, float* __restrict__ out)
{
    int i = blockIdx.x * 256 + threadIdx.x;
    if (i >= N_EDGES / 4) return;
    int4 s4 = ((const int4*)src)[i];
    int4 d4 = ((const int4*)dst)[i];
    float b = blin[0];
    float4 o;
    o.x = s_src[s4.x] + s_dst[d4.x] + b;
    o.y = s_src[s4.y] + s_dst[d4.y] + b;
    o.z = s_src[s4.z] + s_dst[d4.z] + b;
    o.w = s_src[s4.w] + s_dst[d4.w] + b;
    ((float4*)out)[i] = o;
}

extern "C" void kernel_launch(void* const* d_in, const int* in_sizes, int n_in,
                              void* d_out, int out_size, void* d_ws, size_t ws_size,
                              hipStream_t stream) {
    const float* x    = (const float*)d_in[0];
    const int*   ei   = (const int*)d_in[1];
    const float* W1l  = (const float*)d_in[2];
    const float* b1l  = (const float*)d_in[3];
    const float* W1r  = (const float*)d_in[4];
    const float* W2l  = (const float*)d_in[5];
    const float* b2l  = (const float*)d_in[6];
    const float* W2r  = (const float*)d_in[7];
    const float* Wlin = (const float*)d_in[8];
    const float* blin = (const float*)d_in[9];
    float* out = (float*)d_out;

    const int* src = ei;
    const int* dst = ei + N_EDGES;

    // Workspace (~37 MB of 256 MiB; every byte read is written first)
    char* w = (char*)d_ws;
    bf16*  xb    = (bf16*)w;  w += (size_t)N_NODES * 64 * 2;   // 12.8 MB
    bf16*  h1    = (bf16*)w;  w += (size_t)N_NODES * 64 * 2;   // 12.8 MB
    float* ssrc  = (float*)w; w += (size_t)N_NODES * 4;
    float* sdst  = (float*)w; w += (size_t)N_NODES * 4;
    int*   gcur  = (int*)w;   w += 256 * 4;
    bf16*  wb    = (bf16*)w;  w += 16384 * 2;                  // 32 KB bf16 weights
    int*   pk    = (int*)w;   w += (size_t)NBUCK * BCAP * 4;   // 9.6 MB

    const int prep_blocks  = PART_BLOCKS + CONV_BLOCKS; // 6641
    const int fused_blocks = NBUCK * 8;                 // 1568
    const int eo_blocks    = (N_EDGES / 4 + 255) / 256; // 1563

    // ---- pk build + conversions (one concurrent grid) ----
    (void)hipMemsetAsync(gcur, 0, 256 * 4, stream);
    prep_kernel<<<prep_blocks, 256, 0, stream>>>(
        x, xb, W1l, W1r, W2l, W2r, wb, src, dst, gcur, pk);

    // ---- Fused layers (in-LDS neighbor-list build from pk) ----
    layer1_fused<<<fused_blocks, 512, 0, stream>>>(xb, gcur, pk, wb, b1l, h1);
    layer2_fused<<<fused_blocks, 512, 0, stream>>>(h1, gcur, pk, wb + 8192, b2l, Wlin, ssrc, sdst);

    // ---- Edge scores ----
    edge_out_kernel<<<eo_blocks, 256, 0, stream>>>(src, dst, ssrc, sdst, blin, out);
}